// Round 12
// baseline (237.575 us; speedup 1.0000x reference)
//
#include <hip/hip_runtime.h>
#include <hip/hip_fp16.h>
#include <math.h>

#define Bv 4096
#define Sv 64
#define Ev 128
#define Hv 256
#define Cv 18

typedef _Float16 hfrag __attribute__((ext_vector_type(8)));
using f4v = __attribute__((ext_vector_type(4))) float;

#define LO_SCALE 2048.0f            // 2^11 on w_lo
#define LO_DESCALE (1.0f / 2048.0f)

// XOR swizzle: flips bits 2-4 by a hash of higher bits. Bits 0-1 preserved
// -> b128/uint2 contiguity kept; balances scattered writes across banks while
// reads remain the canonical conflict-free lane*16B pattern.
__device__ inline int SW(int o) {
    return o ^ ((((o >> 5) ^ (o >> 8)) & 7) << 2);
}

__device__ inline float fast_tanh(float x) {
    float e = __expf(x + x);
    return 1.0f - 2.0f * __builtin_amdgcn_rcpf(e + 1.0f);
}

__device__ inline unsigned pk_h2(float a, float b) {
    unsigned ua = __half_as_ushort(__float2half_rn(a));
    unsigned ub = __half_as_ushort(__float2half_rn(b));
    return ua | (ub << 16);
}

// convert 8 consecutive W floats at p into f16-hi and f16-lo(*2^11) fragments
__device__ inline void cvt_hilo(const float* p, hfrag& hi, hfrag& lo) {
    float4 a = *(const float4*)p, b = *(const float4*)(p + 4);
    float x[8] = {a.x, a.y, a.z, a.w, b.x, b.y, b.z, b.w};
    unsigned hu[8], lu[8];
    #pragma unroll
    for (int j = 0; j < 8; ++j) {
        __half h = __float2half_rn(x[j]);
        hu[j] = __half_as_ushort(h);
        lu[j] = __half_as_ushort(__float2half_rn((x[j] - __half2float(h)) * LO_SCALE));
    }
    union { uint4 u; hfrag f; } ch, cl;
    ch.u = make_uint4(hu[0] | (hu[1] << 16), hu[2] | (hu[3] << 16),
                      hu[4] | (hu[5] << 16), hu[6] | (hu[7] << 16));
    cl.u = make_uint4(lu[0] | (lu[1] << 16), lu[2] | (lu[3] << 16),
                      lu[4] | (lu[5] << 16), lu[6] | (lu[7] << 16));
    hi = ch.f; lo = cl.f;
}

// ---- single fused kernel: 2 groups x 16 seqs, recurrence + FC head ----
// LDS words: SH[12288] = G0-buf0 | G0-buf1 | G1-buf0 | G1-buf1 (3072 each:
// AH kb0..11; emb kb0-3, h kb4-11). sidx[2048] = token ids [g][t*16+m].
__global__ __launch_bounds__(512, 2) void rnn_all(
    const int* __restrict__ x_in, const int* __restrict__ x_len,
    const float* __restrict__ emb,
    const float* __restrict__ W_ih, const float* __restrict__ W_hh,
    const float* __restrict__ b_ih, const float* __restrict__ b_hh,
    const float* __restrict__ W1, const float* __restrict__ b1,
    const float* __restrict__ W2, const float* __restrict__ b2,
    float* __restrict__ out)
{
    __shared__ unsigned SH[12288];      // 48 KB
    __shared__ int sidx[2048];          // 8 KB
    float* yb = reinterpret_cast<float*>(SH);

    const int tid = threadIdx.x;
    const int lane = tid & 63, w = tid >> 6;     // wave 0..7
    const int q = lane >> 4, col = lane & 15;
    const int rb0 = blockIdx.x * 32;
    const int rb1 = rb0 + 16;

    // ---- inline W fragment build: tiles 2w, 2w+1; hi all 12 kb, lo kb4..11 ----
    hfrag wh[2][12];
    hfrag wl[2][8];
    #pragma unroll
    for (int i = 0; i < 2; ++i) {
        const int n = (2 * w + i) * 16 + col;
        #pragma unroll
        for (int kb = 0; kb < 4; ++kb) {
            hfrag lo_dummy;
            cvt_hilo(&W_ih[n * Ev + kb * 32 + q * 8], wh[i][kb], lo_dummy);
        }
        #pragma unroll
        for (int kb = 4; kb < 12; ++kb)
            cvt_hilo(&W_hh[n * Hv + (kb - 4) * 32 + q * 8], wh[i][kb], wl[i][kb - 4]);
    }
    #pragma unroll
    for (int i = 0; i < 2; ++i) {
        #pragma unroll
        for (int kb = 0; kb < 12; ++kb) asm volatile("" : "+v"(wh[i][kb]));
        #pragma unroll
        for (int kp = 0; kp < 8; ++kp) asm volatile("" : "+v"(wl[i][kp]));
    }

    // bias (n-dependent only -> shared by both groups)
    f4v bcv[2];
    #pragma unroll
    for (int i = 0; i < 2; ++i)
        #pragma unroll
        for (int r = 0; r < 4; ++r) {
            int n = (2 * w + i) * 16 + 4 * q + r;
            bcv[i][r] = b_ih[n] + b_hh[n];
        }
    const int len0 = x_len[rb0 + col];
    const int len1 = x_len[rb1 + col];
    int tmax = len0 > len1 ? len0 : len1;
    #pragma unroll
    for (int m = 1; m < 16; m <<= 1) {
        int o = __shfl_xor(tmax, m, 64);
        tmax = tmax > o ? tmax : o;
    }

    // token table [g*1024 + t*16 + m]
    for (int u = tid; u < 2048; u += 512) {
        int g = u >> 10, tt = (u >> 4) & 63, m = u & 15;
        sidx[u] = x_in[(rb0 + g * 16 + m) * Sv + tt];
    }
    // zero h region of buf0, both groups
    for (int u = tid; u < 2048; u += 512) SH[1024 + u] = 0u;
    for (int u = tid; u < 2048; u += 512) SH[6144 + 1024 + u] = 0u;

    // emb staging geometry: thread stages 4 consecutive k of one row
    const int em = tid >> 5;            // row 0..15
    const int ek = (tid & 31) * 4;      // k 0..124
    const int eo = (ek >> 5) * 256 + ((((ek >> 3) & 3) * 16 + em) * 4) + (((ek >> 2) & 1) * 2);

    // stage emb t=0 both groups; prefetch t=1
    {
        int t0a = x_in[(rb0 + em) * Sv + 0];
        int t0b = x_in[(rb1 + em) * Sv + 0];
        float4 e0 = *(const float4*)&emb[(size_t)t0a * Ev + ek];
        float4 e1 = *(const float4*)&emb[(size_t)t0b * Ev + ek];
        *reinterpret_cast<uint2*>(&SH[SW(eo)]) = make_uint2(pk_h2(e0.x, e0.y), pk_h2(e0.z, e0.w));
        *reinterpret_cast<uint2*>(&SH[6144 + SW(eo)]) = make_uint2(pk_h2(e1.x, e1.y), pk_h2(e1.z, e1.w));
    }
    float4 ev0, ev1;
    {
        int t1a = x_in[(rb0 + em) * Sv + 1];
        int t1b = x_in[(rb1 + em) * Sv + 1];
        ev0 = *(const float4*)&emb[(size_t)t1a * Ev + ek];
        ev1 = *(const float4*)&emb[(size_t)t1b * Ev + ek];
    }
    uint2 snap0[2], snap1[2];
    snap0[0] = snap0[1] = snap1[0] = snap1[1] = make_uint2(0u, 0u);
    __syncthreads();

    #pragma unroll 1
    for (int t = 0; t < tmax; ++t) {
        const int rA = (t & 1) * 3072,        wA = ((t + 1) & 1) * 3072;
        const int rB = 6144 + (t & 1) * 3072, wB = 6144 + ((t + 1) & 1) * 3072;

        // prefetch emb rows for t+2, both groups
        float4 en0, en1;
        if (t + 2 < Sv) {
            int tk0 = sidx[(t + 2) * 16 + em];
            int tk1 = sidx[1024 + (t + 2) * 16 + em];
            en0 = *(const float4*)&emb[(size_t)tk0 * Ev + ek];
            en1 = *(const float4*)&emb[(size_t)tk1 * Ev + ek];
        }

        // ================= group 0 phase =================
        {
            f4v aHe0 = bcv[0], aHe1 = bcv[1];
            f4v z = {0.f, 0.f, 0.f, 0.f};
            f4v aHo0 = z, aHo1 = z, aL0 = z, aL1 = z;
            #pragma unroll
            for (int kb = 0; kb < 4; ++kb) {
                hfrag ah = *reinterpret_cast<const hfrag*>(&SH[rA + SW(kb * 256 + lane * 4)]);
                if (kb & 1) {
                    aHo0 = __builtin_amdgcn_mfma_f32_16x16x32_f16(wh[0][kb], ah, aHo0, 0, 0, 0);
                    aHo1 = __builtin_amdgcn_mfma_f32_16x16x32_f16(wh[1][kb], ah, aHo1, 0, 0, 0);
                } else {
                    aHe0 = __builtin_amdgcn_mfma_f32_16x16x32_f16(wh[0][kb], ah, aHe0, 0, 0, 0);
                    aHe1 = __builtin_amdgcn_mfma_f32_16x16x32_f16(wh[1][kb], ah, aHe1, 0, 0, 0);
                }
            }
            #pragma unroll
            for (int kb = 4; kb < 12; ++kb) {
                hfrag ah = *reinterpret_cast<const hfrag*>(&SH[rA + SW(kb * 256 + lane * 4)]);
                if (kb & 1) {
                    aHo0 = __builtin_amdgcn_mfma_f32_16x16x32_f16(wh[0][kb], ah, aHo0, 0, 0, 0);
                    aHo1 = __builtin_amdgcn_mfma_f32_16x16x32_f16(wh[1][kb], ah, aHo1, 0, 0, 0);
                } else {
                    aHe0 = __builtin_amdgcn_mfma_f32_16x16x32_f16(wh[0][kb], ah, aHe0, 0, 0, 0);
                    aHe1 = __builtin_amdgcn_mfma_f32_16x16x32_f16(wh[1][kb], ah, aHe1, 0, 0, 0);
                }
                aL0 = __builtin_amdgcn_mfma_f32_16x16x32_f16(wl[0][kb - 4], ah, aL0, 0, 0, 0);
                aL1 = __builtin_amdgcn_mfma_f32_16x16x32_f16(wl[1][kb - 4], ah, aL1, 0, 0, 0);
            }
            #pragma unroll
            for (int i = 0; i < 2; ++i) {
                f4v s  = (i == 0) ? (aHe0 + aHo0) : (aHe1 + aHo1);
                f4v sl = (i == 0) ? aL0 : aL1;
                const int ti = 2 * w + i;
                float hv[4];
                #pragma unroll
                for (int r = 0; r < 4; ++r)
                    hv[r] = fast_tanh(s[r] + sl[r] * LO_DESCALE);
                const int dl = ((ti & 1) * 2 + (q >> 1)) * 16 + col;
                const uint2 hu = make_uint2(pk_h2(hv[0], hv[1]), pk_h2(hv[2], hv[3]));
                const int oAH = (4 + (ti >> 1)) * 256 + dl * 4 + (q & 1) * 2;
                *reinterpret_cast<uint2*>(&SH[wA + SW(oAH)]) = hu;
                if (t == len0 - 1) snap0[i] = hu;
            }
            if (t + 1 < Sv)
                *reinterpret_cast<uint2*>(&SH[wA + SW(eo)]) =
                    make_uint2(pk_h2(ev0.x, ev0.y), pk_h2(ev0.z, ev0.w));
        }

        // ================= group 1 phase =================
        {
            f4v aHe0 = bcv[0], aHe1 = bcv[1];
            f4v z = {0.f, 0.f, 0.f, 0.f};
            f4v aHo0 = z, aHo1 = z, aL0 = z, aL1 = z;
            #pragma unroll
            for (int kb = 0; kb < 4; ++kb) {
                hfrag ah = *reinterpret_cast<const hfrag*>(&SH[rB + SW(kb * 256 + lane * 4)]);
                if (kb & 1) {
                    aHo0 = __builtin_amdgcn_mfma_f32_16x16x32_f16(wh[0][kb], ah, aHo0, 0, 0, 0);
                    aHo1 = __builtin_amdgcn_mfma_f32_16x16x32_f16(wh[1][kb], ah, aHo1, 0, 0, 0);
                } else {
                    aHe0 = __builtin_amdgcn_mfma_f32_16x16x32_f16(wh[0][kb], ah, aHe0, 0, 0, 0);
                    aHe1 = __builtin_amdgcn_mfma_f32_16x16x32_f16(wh[1][kb], ah, aHe1, 0, 0, 0);
                }
            }
            #pragma unroll
            for (int kb = 4; kb < 12; ++kb) {
                hfrag ah = *reinterpret_cast<const hfrag*>(&SH[rB + SW(kb * 256 + lane * 4)]);
                if (kb & 1) {
                    aHo0 = __builtin_amdgcn_mfma_f32_16x16x32_f16(wh[0][kb], ah, aHo0, 0, 0, 0);
                    aHo1 = __builtin_amdgcn_mfma_f32_16x16x32_f16(wh[1][kb], ah, aHo1, 0, 0, 0);
                } else {
                    aHe0 = __builtin_amdgcn_mfma_f32_16x16x32_f16(wh[0][kb], ah, aHe0, 0, 0, 0);
                    aHe1 = __builtin_amdgcn_mfma_f32_16x16x32_f16(wh[1][kb], ah, aHe1, 0, 0, 0);
                }
                aL0 = __builtin_amdgcn_mfma_f32_16x16x32_f16(wl[0][kb - 4], ah, aL0, 0, 0, 0);
                aL1 = __builtin_amdgcn_mfma_f32_16x16x32_f16(wl[1][kb - 4], ah, aL1, 0, 0, 0);
            }
            #pragma unroll
            for (int i = 0; i < 2; ++i) {
                f4v s  = (i == 0) ? (aHe0 + aHo0) : (aHe1 + aHo1);
                f4v sl = (i == 0) ? aL0 : aL1;
                const int ti = 2 * w + i;
                float hv[4];
                #pragma unroll
                for (int r = 0; r < 4; ++r)
                    hv[r] = fast_tanh(s[r] + sl[r] * LO_DESCALE);
                const int dl = ((ti & 1) * 2 + (q >> 1)) * 16 + col;
                const uint2 hu = make_uint2(pk_h2(hv[0], hv[1]), pk_h2(hv[2], hv[3]));
                const int oAH = (4 + (ti >> 1)) * 256 + dl * 4 + (q & 1) * 2;
                *reinterpret_cast<uint2*>(&SH[wB + SW(oAH)]) = hu;
                if (t == len1 - 1) snap1[i] = hu;
            }
            if (t + 1 < Sv)
                *reinterpret_cast<uint2*>(&SH[wB + SW(eo)]) =
                    make_uint2(pk_h2(ev1.x, ev1.y), pk_h2(ev1.z, ev1.w));
        }

        ev0 = en0; ev1 = en1;
        __syncthreads();
    }

    // ---- write last-h snapshots to LDS (LF0 at 0, LF1 at 2048) ----
    #pragma unroll
    for (int i = 0; i < 2; ++i) {
        const int ti = 2 * w + i;
        const int dl = ((ti & 1) * 2 + (q >> 1)) * 16 + col;
        const int oLH = (ti >> 1) * 256 + dl * 4 + (q & 1) * 2;
        *reinterpret_cast<uint2*>(&SH[SW(oLH)]) = snap0[i];
        *reinterpret_cast<uint2*>(&SH[2048 + SW(oLH)]) = snap1[i];
    }
    __syncthreads();

    // ---- FC1 (MFMA, f16 hi+lo), W1 converted inline, both groups ----
    f4v fH[2][2], fL[2][2];
    #pragma unroll
    for (int i = 0; i < 2; ++i) {
        float4 bb = *(const float4*)&b1[(2 * w + i) * 16 + 4 * q];
        f4v bv = (f4v){bb.x, bb.y, bb.z, bb.w};
        f4v z = {0.f, 0.f, 0.f, 0.f};
        fH[0][i] = bv; fH[1][i] = bv;
        fL[0][i] = z;  fL[1][i] = z;
    }
    #pragma unroll
    for (int kb = 0; kb < 8; ++kb) {
        hfrag a0 = *reinterpret_cast<const hfrag*>(&SH[SW(kb * 256 + lane * 4)]);
        hfrag a1 = *reinterpret_cast<const hfrag*>(&SH[2048 + SW(kb * 256 + lane * 4)]);
        #pragma unroll
        for (int i = 0; i < 2; ++i) {
            const int n = (2 * w + i) * 16 + col;
            hfrag w1h, w1l;
            cvt_hilo(&W1[n * Hv + kb * 32 + q * 8], w1h, w1l);
            fH[0][i] = __builtin_amdgcn_mfma_f32_16x16x32_f16(w1h, a0, fH[0][i], 0, 0, 0);
            fL[0][i] = __builtin_amdgcn_mfma_f32_16x16x32_f16(w1l, a0, fL[0][i], 0, 0, 0);
            fH[1][i] = __builtin_amdgcn_mfma_f32_16x16x32_f16(w1h, a1, fH[1][i], 0, 0, 0);
            fL[1][i] = __builtin_amdgcn_mfma_f32_16x16x32_f16(w1l, a1, fL[1][i], 0, 0, 0);
        }
    }
    __syncthreads();   // LF reads done before yb overwrite

    // y = relu(...) into yb[(g*16+col)*260 + n]
    #pragma unroll
    for (int g = 0; g < 2; ++g)
        #pragma unroll
        for (int i = 0; i < 2; ++i) {
            int n0 = (2 * w + i) * 16 + 4 * q;
            float4 yv;
            yv.x = fmaxf(fH[g][i][0] + fL[g][i][0] * LO_DESCALE, 0.f);
            yv.y = fmaxf(fH[g][i][1] + fL[g][i][1] * LO_DESCALE, 0.f);
            yv.z = fmaxf(fH[g][i][2] + fL[g][i][2] * LO_DESCALE, 0.f);
            yv.w = fmaxf(fH[g][i][3] + fL[g][i][3] * LO_DESCALE, 0.f);
            *reinterpret_cast<float4*>(&yb[(g * 16 + col) * 260 + n0]) = yv;
        }
    __syncthreads();

    // ---- FC2: 32 x 18 dots of length 256 ----
    for (int p = tid; p < 32 * Cv; p += 512) {
        int r = p & 31, cc = p >> 5;
        float s = b2[cc];
        #pragma unroll 8
        for (int k4 = 0; k4 < Hv / 4; ++k4) {
            float4 yv = *reinterpret_cast<const float4*>(&yb[r * 260 + 4 * k4]);
            float4 wv2 = *(const float4*)&W2[cc * Hv + 4 * k4];
            s = fmaf(yv.x, wv2.x, s);
            s = fmaf(yv.y, wv2.y, s);
            s = fmaf(yv.z, wv2.z, s);
            s = fmaf(yv.w, wv2.w, s);
        }
        int row = (r < 16) ? (rb0 + r) : (rb1 + r - 16);
        out[row * Cv + cc] = s;
    }
}

extern "C" void kernel_launch(void* const* d_in, const int* in_sizes, int n_in,
                              void* d_out, int out_size, void* d_ws, size_t ws_size,
                              hipStream_t stream) {
    const int*   x_in  = (const int*)  d_in[0];
    const int*   x_len = (const int*)  d_in[1];
    const float* emb   = (const float*)d_in[2];
    const float* W_ih  = (const float*)d_in[3];
    const float* W_hh  = (const float*)d_in[4];
    const float* b_ih  = (const float*)d_in[5];
    const float* b_hh  = (const float*)d_in[6];
    const float* W1    = (const float*)d_in[7];
    const float* b1    = (const float*)d_in[8];
    const float* W2    = (const float*)d_in[9];
    const float* b2    = (const float*)d_in[10];
    float* out = (float*)d_out;

    rnn_all<<<Bv / 32, 512, 0, stream>>>(x_in, x_len, emb, W_ih, W_hh,
                                         b_ih, b_hh, W1, b1, W2, b2, out);
}

// Round 14
// 161.471 us; speedup vs baseline: 1.4713x; 1.4713x over previous
//
#include <hip/hip_runtime.h>
#include <hip/hip_fp16.h>
#include <math.h>

#define Bv 4096
#define Sv 64
#define Ev 128
#define Hv 256
#define Cv 18
#define Mrows 16
#define WRDS 3072    // words per step buffer: AH kb0..11 (emb kb0-3, h kb4-11)

typedef _Float16 hfrag __attribute__((ext_vector_type(8)));
using f4v = __attribute__((ext_vector_type(4))) float;

#define LO_SCALE 2048.0f            // 2^11 on w_lo
#define LO_DESCALE (1.0f / 2048.0f)

// XOR swizzle: flips bits 2-4 by a hash of higher bits. Bits 0-1 preserved
// -> b128/uint2 contiguity kept; balances scattered writes across banks while
// reads remain the canonical conflict-free lane*16B pattern.
__device__ inline int SW(int o) {
    return o ^ ((((o >> 5) ^ (o >> 8)) & 7) << 2);
}

__device__ inline float fast_tanh(float x) {
    float e = __expf(x + x);
    return 1.0f - 2.0f * __builtin_amdgcn_rcpf(e + 1.0f);
}

__device__ inline unsigned pk_h2(float a, float b) {
    unsigned ua = __half_as_ushort(__float2half_rn(a));
    unsigned ub = __half_as_ushort(__float2half_rn(b));
    return ua | (ub << 16);
}

// ---- kernel A: build MFMA fragments (f16 hi + f16 lo*2^11) for rnn W and W1 ----
__global__ void build_frags(const float* __restrict__ W_ih,
                            const float* __restrict__ W_hh,
                            const float* __restrict__ W1,
                            unsigned* __restrict__ wfh,  unsigned* __restrict__ wfl,
                            unsigned* __restrict__ wf1h, unsigned* __restrict__ wf1l) {
    int f = blockIdx.x * 256 + threadIdx.x;   // 0..20479
    bool isrnn = f < 12288;
    int g = isrnn ? f : f - 12288;
    int lane = g & 63, tile = (g >> 6) & 15, kb = g >> 10;
    int q = lane >> 4, col = lane & 15;
    int n = tile * 16 + col;
    unsigned hu[8], lu[8];
    #pragma unroll
    for (int j = 0; j < 8; ++j) {
        int k = kb * 32 + q * 8 + j;
        float x;
        if (isrnn) x = (k < Ev) ? W_ih[n * Ev + k] : W_hh[n * Hv + (k - Ev)];
        else       x = W1[n * Hv + k];
        __half h = __float2half_rn(x);
        hu[j] = __half_as_ushort(h);
        float l = (x - __half2float(h)) * LO_SCALE;
        lu[j] = __half_as_ushort(__float2half_rn(l));
    }
    unsigned* oh = (isrnn ? wfh : wf1h) + (size_t)g * 4;
    unsigned* ol = (isrnn ? wfl : wf1l) + (size_t)g * 4;
    #pragma unroll
    for (int d = 0; d < 4; ++d) {
        oh[d] = hu[2 * d] | (hu[2 * d + 1] << 16);
        ol[d] = lu[2 * d] | (lu[2 * d + 1] << 16);
    }
}

// ---- kernel B: fused recurrence + FC head; 8 waves x 2 N-tiles, W pinned ----
__global__ __launch_bounds__(512, 2) void rnn_fused(
    const int* __restrict__ x_in, const int* __restrict__ x_len,
    const float* __restrict__ emb,
    const unsigned* __restrict__ wfh, const unsigned* __restrict__ wfl,
    const unsigned* __restrict__ wf1h, const unsigned* __restrict__ wf1l,
    const float* __restrict__ b_ih, const float* __restrict__ b_hh,
    const float* __restrict__ b1, const float* __restrict__ W2,
    const float* __restrict__ b2, float* __restrict__ out)
{
    __shared__ unsigned SH[2 * WRDS];   // 24 KB step buffers (f16 A fragments)
    __shared__ unsigned LF[2048];       // 8 KB last-h fragments (hi only)
    __shared__ int sidx[Mrows * Sv];    // 4 KB token ids, [t*16 + m]
    float* yb = reinterpret_cast<float*>(SH);   // fc y buffer aliases SH after loop

    const int tid = threadIdx.x;
    const int lane = tid & 63, w = tid >> 6;     // wave 0..7
    const int q = lane >> 4, col = lane & 15;
    const int rb = blockIdx.x * Mrows;

    // resident W: tiles 2w, 2w+1 -> f16 hi all 12 kb (96 regs) + f16 lo kb4..11 (64)
    hfrag wh[2][12];
    hfrag wl[2][8];
    #pragma unroll
    for (int i = 0; i < 2; ++i) {
        const int ti = 2 * w + i;
        #pragma unroll
        for (int kb = 0; kb < 12; ++kb) {
            int fid = (kb * 16 + ti) * 64 + lane;
            wh[i][kb] = *reinterpret_cast<const hfrag*>(&wfh[(size_t)fid * 4]);
        }
        #pragma unroll
        for (int kp = 0; kp < 8; ++kp) {
            int fid = ((kp + 4) * 16 + ti) * 64 + lane;
            wl[i][kp] = *reinterpret_cast<const hfrag*>(&wfl[(size_t)fid * 4]);
        }
    }
    #pragma unroll
    for (int i = 0; i < 2; ++i) {
        #pragma unroll
        for (int kb = 0; kb < 12; ++kb) asm volatile("" : "+v"(wh[i][kb]));
        #pragma unroll
        for (int kp = 0; kp < 8; ++kp) asm volatile("" : "+v"(wl[i][kp]));
    }

    // bias folded into MFMA C-init
    f4v bcv[2];
    #pragma unroll
    for (int i = 0; i < 2; ++i)
        #pragma unroll
        for (int r = 0; r < 4; ++r) {
            int n = (2 * w + i) * 16 + 4 * q + r;
            bcv[i][r] = b_ih[n] + b_hh[n];
        }
    const int len_c = x_len[rb + col];
    int tmax = len_c;
    #pragma unroll
    for (int m = 1; m < 16; m <<= 1) {
        int o = __shfl_xor(tmax, m, 64);
        tmax = tmax > o ? tmax : o;
    }

    // token table, transposed [t*16 + m]
    for (int u = tid; u < Mrows * Sv; u += 512) {
        int tt = u & 63, m = u >> 6;
        sidx[tt * 16 + m] = x_in[(rb + m) * Sv + tt];
    }
    // zero h region of buffer 0 (words 1024..3071; SW permutes within)
    for (int u = tid; u < 2048; u += 512) SH[1024 + u] = 0u;

    // emb staging geometry: thread stages 4 consecutive k of one row
    const int em = tid >> 5;            // row 0..15
    const int ek = (tid & 31) * 4;      // k 0..124
    const int eo = (ek >> 5) * 256 + ((((ek >> 3) & 3) * 16 + em) * 4) + (((ek >> 2) & 1) * 2);

    // stage emb for t=0; prefetch row for t=1 (depth-2 pipeline)
    {
        int tok0 = x_in[(rb + em) * Sv + 0];
        float4 e0 = *(const float4*)&emb[(size_t)tok0 * Ev + ek];
        *reinterpret_cast<uint2*>(&SH[SW(eo)]) =
            make_uint2(pk_h2(e0.x, e0.y), pk_h2(e0.z, e0.w));
    }
    float4 ev_cur;
    {
        int tok1 = x_in[(rb + em) * Sv + 1];
        ev_cur = *(const float4*)&emb[(size_t)tok1 * Ev + ek];
    }
    uint2 snap[2];
    snap[0] = snap[1] = make_uint2(0u, 0u);
    __syncthreads();

    #pragma unroll 1
    for (int t = 0; t < tmax; ++t) {
        const int rbuf = (t & 1) * WRDS;
        const int wbuf = ((t + 1) & 1) * WRDS;

        // prefetch emb row for t+2 (full step of latency budget)
        float4 ev_next;
        if (t + 2 < Sv) {
            int tok = sidx[(t + 2) * 16 + em];
            ev_next = *(const float4*)&emb[(size_t)tok * Ev + ek];
        }

        // 8 accumulator chains: hi even/odd per tile + lo even/odd per tile
        f4v aHe0 = bcv[0], aHe1 = bcv[1];
        f4v z = {0.f, 0.f, 0.f, 0.f};
        f4v aHo0 = z, aHo1 = z, aLe0 = z, aLe1 = z, aLo0 = z, aLo1 = z;

        #pragma unroll
        for (int kb = 0; kb < 4; ++kb) {
            hfrag ah = *reinterpret_cast<const hfrag*>(&SH[rbuf + SW(kb * 256 + lane * 4)]);
            if (kb & 1) {
                aHo0 = __builtin_amdgcn_mfma_f32_16x16x32_f16(wh[0][kb], ah, aHo0, 0, 0, 0);
                aHo1 = __builtin_amdgcn_mfma_f32_16x16x32_f16(wh[1][kb], ah, aHo1, 0, 0, 0);
            } else {
                aHe0 = __builtin_amdgcn_mfma_f32_16x16x32_f16(wh[0][kb], ah, aHe0, 0, 0, 0);
                aHe1 = __builtin_amdgcn_mfma_f32_16x16x32_f16(wh[1][kb], ah, aHe1, 0, 0, 0);
            }
        }
        #pragma unroll
        for (int kb = 4; kb < 12; ++kb) {
            hfrag ah = *reinterpret_cast<const hfrag*>(&SH[rbuf + SW(kb * 256 + lane * 4)]);
            if (kb & 1) {
                aHo0 = __builtin_amdgcn_mfma_f32_16x16x32_f16(wh[0][kb], ah, aHo0, 0, 0, 0);
                aHo1 = __builtin_amdgcn_mfma_f32_16x16x32_f16(wh[1][kb], ah, aHo1, 0, 0, 0);
                aLo0 = __builtin_amdgcn_mfma_f32_16x16x32_f16(wl[0][kb - 4], ah, aLo0, 0, 0, 0);
                aLo1 = __builtin_amdgcn_mfma_f32_16x16x32_f16(wl[1][kb - 4], ah, aLo1, 0, 0, 0);
            } else {
                aHe0 = __builtin_amdgcn_mfma_f32_16x16x32_f16(wh[0][kb], ah, aHe0, 0, 0, 0);
                aHe1 = __builtin_amdgcn_mfma_f32_16x16x32_f16(wh[1][kb], ah, aHe1, 0, 0, 0);
                aLe0 = __builtin_amdgcn_mfma_f32_16x16x32_f16(wl[0][kb - 4], ah, aLe0, 0, 0, 0);
                aLe1 = __builtin_amdgcn_mfma_f32_16x16x32_f16(wl[1][kb - 4], ah, aLe1, 0, 0, 0);
            }
        }

        // stage emb for t+1 early: independent of this step's MFMA results,
        // so it overlaps the MFMA tail instead of extending the epilogue.
        if (t + 1 < Sv) {
            *reinterpret_cast<uint2*>(&SH[wbuf + SW(eo)]) =
                make_uint2(pk_h2(ev_cur.x, ev_cur.y), pk_h2(ev_cur.z, ev_cur.w));
        }

        // epilogue: lane holds h[m=col][n = ti*16 + 4q + r]
        #pragma unroll
        for (int i = 0; i < 2; ++i) {
            f4v s  = (i == 0) ? (aHe0 + aHo0) : (aHe1 + aHo1);
            f4v sl = (i == 0) ? (aLe0 + aLo0) : (aLe1 + aLo1);
            const int ti = 2 * w + i;
            float hv[4];
            #pragma unroll
            for (int r = 0; r < 4; ++r)
                hv[r] = fast_tanh(s[r] + sl[r] * LO_DESCALE);
            const int dl = ((ti & 1) * 2 + (q >> 1)) * 16 + col;
            const uint2 hu = make_uint2(pk_h2(hv[0], hv[1]), pk_h2(hv[2], hv[3]));
            const int oAH = (4 + (ti >> 1)) * 256 + dl * 4 + (q & 1) * 2;
            *reinterpret_cast<uint2*>(&SH[wbuf + SW(oAH)]) = hu;
            if (t == len_c - 1) snap[i] = hu;   // register snapshot, no LDS write
        }
        ev_cur = ev_next;
        __syncthreads();
    }

    // ---- write last-h snapshots to LF once ----
    #pragma unroll
    for (int i = 0; i < 2; ++i) {
        const int ti = 2 * w + i;
        const int dl = ((ti & 1) * 2 + (q >> 1)) * 16 + col;
        const int oLH = (ti >> 1) * 256 + dl * 4 + (q & 1) * 2;
        *reinterpret_cast<uint2*>(&LF[SW(oLH)]) = snap[i];
    }
    __syncthreads();

    // ---- fused FC1 (MFMA, f16 hi+lo) on LF ----
    f4v fH0, fH1, fL0, fL1;
    {
        float4 bb0 = *(const float4*)&b1[(2 * w) * 16 + 4 * q];
        float4 bb1 = *(const float4*)&b1[(2 * w + 1) * 16 + 4 * q];
        fH0 = (f4v){bb0.x, bb0.y, bb0.z, bb0.w};
        fH1 = (f4v){bb1.x, bb1.y, bb1.z, bb1.w};
        f4v z = {0.f, 0.f, 0.f, 0.f};
        fL0 = z; fL1 = z;
    }
    #pragma unroll
    for (int kb = 0; kb < 8; ++kb) {
        hfrag ah = *reinterpret_cast<const hfrag*>(&LF[SW(kb * 256 + lane * 4)]);
        int fid0 = (kb * 16 + 2 * w) * 64 + lane;
        int fid1 = fid0 + 64;
        hfrag w0h = *reinterpret_cast<const hfrag*>(&wf1h[(size_t)fid0 * 4]);
        hfrag w1h = *reinterpret_cast<const hfrag*>(&wf1h[(size_t)fid1 * 4]);
        hfrag w0l = *reinterpret_cast<const hfrag*>(&wf1l[(size_t)fid0 * 4]);
        hfrag w1l = *reinterpret_cast<const hfrag*>(&wf1l[(size_t)fid1 * 4]);
        fH0 = __builtin_amdgcn_mfma_f32_16x16x32_f16(w0h, ah, fH0, 0, 0, 0);
        fH1 = __builtin_amdgcn_mfma_f32_16x16x32_f16(w1h, ah, fH1, 0, 0, 0);
        fL0 = __builtin_amdgcn_mfma_f32_16x16x32_f16(w0l, ah, fL0, 0, 0, 0);
        fL1 = __builtin_amdgcn_mfma_f32_16x16x32_f16(w1l, ah, fL1, 0, 0, 0);
    }

    // y = relu(...) into yb (aliases SH; step buffers dead here)
    #pragma unroll
    for (int i = 0; i < 2; ++i) {
        int n0 = (2 * w + i) * 16 + 4 * q;
        f4v s = (i == 0) ? fH0 : fH1;
        f4v sl = (i == 0) ? fL0 : fL1;
        float4 yv;
        yv.x = fmaxf(s[0] + sl[0] * LO_DESCALE, 0.f);
        yv.y = fmaxf(s[1] + sl[1] * LO_DESCALE, 0.f);
        yv.z = fmaxf(s[2] + sl[2] * LO_DESCALE, 0.f);
        yv.w = fmaxf(s[3] + sl[3] * LO_DESCALE, 0.f);
        *reinterpret_cast<float4*>(&yb[col * 260 + n0]) = yv;
    }
    __syncthreads();

    // ---- FC2: 16 x 18 dots of length 256 ----
    if (tid < Mrows * Cv) {
        int r = tid & 15, cc = tid >> 4;
        float s = b2[cc];
        #pragma unroll 8
        for (int k4 = 0; k4 < Hv / 4; ++k4) {
            float4 yv = *reinterpret_cast<const float4*>(&yb[r * 260 + 4 * k4]);
            float4 wv2 = *(const float4*)&W2[cc * Hv + 4 * k4];
            s = fmaf(yv.x, wv2.x, s);
            s = fmaf(yv.y, wv2.y, s);
            s = fmaf(yv.z, wv2.z, s);
            s = fmaf(yv.w, wv2.w, s);
        }
        out[(rb + r) * Cv + cc] = s;
    }
}

extern "C" void kernel_launch(void* const* d_in, const int* in_sizes, int n_in,
                              void* d_out, int out_size, void* d_ws, size_t ws_size,
                              hipStream_t stream) {
    const int*   x_in  = (const int*)  d_in[0];
    const int*   x_len = (const int*)  d_in[1];
    const float* emb   = (const float*)d_in[2];
    const float* W_ih  = (const float*)d_in[3];
    const float* W_hh  = (const float*)d_in[4];
    const float* b_ih  = (const float*)d_in[5];
    const float* b_hh  = (const float*)d_in[6];
    const float* W1    = (const float*)d_in[7];
    const float* b1    = (const float*)d_in[8];
    const float* W2    = (const float*)d_in[9];
    const float* b2    = (const float*)d_in[10];
    float* out = (float*)d_out;

    unsigned* wfh  = (unsigned*)d_ws;         // 12288 frags * 16 B
    unsigned* wfl  = wfh  + 12288 * 4;        // 12288 * 16 B
    unsigned* wf1h = wfl  + 12288 * 4;        // 8192 * 16 B
    unsigned* wf1l = wf1h + 8192 * 4;         // 8192 * 16 B

    build_frags<<<80, 256, 0, stream>>>(W_ih, W_hh, W1, wfh, wfl, wf1h, wf1l);
    rnn_fused<<<Bv / Mrows, 512, 0, stream>>>(x_in, x_len, emb, wfh, wfl,
                                              wf1h, wf1l, b_ih, b_hh,
                                              b1, W2, b2, out);
}

// Round 15
// 146.770 us; speedup vs baseline: 1.6187x; 1.1002x over previous
//
#include <hip/hip_runtime.h>
#include <hip/hip_fp16.h>
#include <math.h>

#define Bv 4096
#define Sv 64
#define Ev 128
#define Hv 256
#define Cv 18
#define Mrows 16
#define WRDS 3072    // words per step buffer: AH kb0..11 (emb kb0-3, h kb4-11)

typedef _Float16 hfrag __attribute__((ext_vector_type(8)));
using f4v = __attribute__((ext_vector_type(4))) float;

#define LO_SCALE 2048.0f            // 2^11 on w1_lo (FC1 only)
#define LO_DESCALE (1.0f / 2048.0f)

// XOR swizzle: flips bits 2-4 by a hash of higher bits. Bits 0-1 preserved
// -> b128/uint2 contiguity kept; balances scattered writes across banks while
// reads remain the canonical conflict-free lane*16B pattern.
__device__ inline int SW(int o) {
    return o ^ ((((o >> 5) ^ (o >> 8)) & 7) << 2);
}

__device__ inline float fast_tanh(float x) {
    float e = __expf(x + x);
    return 1.0f - 2.0f * __builtin_amdgcn_rcpf(e + 1.0f);
}

__device__ inline unsigned pk_h2(float a, float b) {
    unsigned ua = __half_as_ushort(__float2half_rn(a));
    unsigned ub = __half_as_ushort(__float2half_rn(b));
    return ua | (ub << 16);
}

// ---- kernel A: build MFMA fragments: rnn W (f16 hi only), W1 (hi + lo*2^11) ----
__global__ void build_frags(const float* __restrict__ W_ih,
                            const float* __restrict__ W_hh,
                            const float* __restrict__ W1,
                            unsigned* __restrict__ wfh,
                            unsigned* __restrict__ wf1h, unsigned* __restrict__ wf1l) {
    int f = blockIdx.x * 256 + threadIdx.x;   // 0..20479
    bool isrnn = f < 12288;
    int g = isrnn ? f : f - 12288;
    int lane = g & 63, tile = (g >> 6) & 15, kb = g >> 10;
    int q = lane >> 4, col = lane & 15;
    int n = tile * 16 + col;
    unsigned hu[8], lu[8];
    #pragma unroll
    for (int j = 0; j < 8; ++j) {
        int k = kb * 32 + q * 8 + j;
        float x;
        if (isrnn) x = (k < Ev) ? W_ih[n * Ev + k] : W_hh[n * Hv + (k - Ev)];
        else       x = W1[n * Hv + k];
        __half h = __float2half_rn(x);
        hu[j] = __half_as_ushort(h);
        float l = (x - __half2float(h)) * LO_SCALE;
        lu[j] = __half_as_ushort(__float2half_rn(l));
    }
    unsigned* oh = (isrnn ? wfh : wf1h) + (size_t)g * 4;
    #pragma unroll
    for (int d = 0; d < 4; ++d) oh[d] = hu[2 * d] | (hu[2 * d + 1] << 16);
    if (!isrnn) {
        unsigned* ol = wf1l + (size_t)g * 4;
        #pragma unroll
        for (int d = 0; d < 4; ++d) ol[d] = lu[2 * d] | (lu[2 * d + 1] << 16);
    }
}

// ---- kernel B: fused recurrence + FC head; 8 waves x 2 N-tiles, W pinned ----
__global__ __launch_bounds__(512, 2) void rnn_fused(
    const int* __restrict__ x_in, const int* __restrict__ x_len,
    const float* __restrict__ emb,
    const unsigned* __restrict__ wfh,
    const unsigned* __restrict__ wf1h, const unsigned* __restrict__ wf1l,
    const float* __restrict__ b_ih, const float* __restrict__ b_hh,
    const float* __restrict__ b1, const float* __restrict__ W2,
    const float* __restrict__ b2, float* __restrict__ out)
{
    __shared__ unsigned SH[2 * WRDS];   // 24 KB step buffers (f16 A fragments)
    __shared__ unsigned LF[2048];       // 8 KB last-h fragments
    float* yb = reinterpret_cast<float*>(SH);   // fc y buffer aliases SH after loop

    const int tid = threadIdx.x;
    const int lane = tid & 63, w = tid >> 6;     // wave 0..7
    const int q = lane >> 4, col = lane & 15;
    const int rb = blockIdx.x * Mrows;

    // resident W: tiles 2w, 2w+1 -> f16 hi all 12 kb (96 regs)
    hfrag wh[2][12];
    #pragma unroll
    for (int i = 0; i < 2; ++i) {
        const int ti = 2 * w + i;
        #pragma unroll
        for (int kb = 0; kb < 12; ++kb) {
            int fid = (kb * 16 + ti) * 64 + lane;
            wh[i][kb] = *reinterpret_cast<const hfrag*>(&wfh[(size_t)fid * 4]);
        }
    }
    #pragma unroll
    for (int i = 0; i < 2; ++i)
        #pragma unroll
        for (int kb = 0; kb < 12; ++kb) asm volatile("" : "+v"(wh[i][kb]));

    // bias folded into MFMA C-init
    f4v bcv[2];
    #pragma unroll
    for (int i = 0; i < 2; ++i)
        #pragma unroll
        for (int r = 0; r < 4; ++r) {
            int n = (2 * w + i) * 16 + 4 * q + r;
            bcv[i][r] = b_ih[n] + b_hh[n];
        }
    const int len_c = x_len[rb + col];
    int tmax = len_c;
    #pragma unroll
    for (int m = 1; m < 16; m <<= 1) {
        int o = __shfl_xor(tmax, m, 64);
        tmax = tmax > o ? tmax : o;
    }

    // zero h region of buffer 0 (words 1024..3071; SW permutes within)
    for (int u = tid; u < 2048; u += 512) SH[1024 + u] = 0u;

    // emb staging geometry: thread stages 4 consecutive k of one row
    const int em = tid >> 5;            // row 0..15
    const int ek = (tid & 31) * 4;      // k 0..124
    const int eo = (ek >> 5) * 256 + ((((ek >> 3) & 3) * 16 + em) * 4) + (((ek >> 2) & 1) * 2);
    const int* xrow = x_in + (rb + em) * Sv;

    // stage emb for t=0; prefetch row for t=1 (depth-2 pipeline)
    {
        float4 e0 = *(const float4*)&emb[(size_t)xrow[0] * Ev + ek];
        *reinterpret_cast<uint2*>(&SH[SW(eo)]) =
            make_uint2(pk_h2(e0.x, e0.y), pk_h2(e0.z, e0.w));
    }
    float4 ev_cur = *(const float4*)&emb[(size_t)xrow[1] * Ev + ek];
    uint2 snap[2];
    snap[0] = snap[1] = make_uint2(0u, 0u);
    __syncthreads();

    #pragma unroll 1
    for (int t = 0; t < tmax; ++t) {
        const int rbuf = (t & 1) * WRDS;
        const int wbuf = ((t + 1) & 1) * WRDS;

        // prefetch emb row for t+2 (token read is L1-hot global, vmem pipe idle)
        float4 ev_next;
        if (t + 2 < Sv) {
            int tok = xrow[t + 2];
            ev_next = *(const float4*)&emb[(size_t)tok * Ev + ek];
        }

        // 4 accumulator chains: hi even/odd per tile, bias folded in even
        f4v aHe0 = bcv[0], aHe1 = bcv[1];
        f4v z = {0.f, 0.f, 0.f, 0.f};
        f4v aHo0 = z, aHo1 = z;

        #pragma unroll
        for (int kb = 0; kb < 12; ++kb) {
            hfrag ah = *reinterpret_cast<const hfrag*>(&SH[rbuf + SW(kb * 256 + lane * 4)]);
            if (kb & 1) {
                aHo0 = __builtin_amdgcn_mfma_f32_16x16x32_f16(wh[0][kb], ah, aHo0, 0, 0, 0);
                aHo1 = __builtin_amdgcn_mfma_f32_16x16x32_f16(wh[1][kb], ah, aHo1, 0, 0, 0);
            } else {
                aHe0 = __builtin_amdgcn_mfma_f32_16x16x32_f16(wh[0][kb], ah, aHe0, 0, 0, 0);
                aHe1 = __builtin_amdgcn_mfma_f32_16x16x32_f16(wh[1][kb], ah, aHe1, 0, 0, 0);
            }
        }

        // stage emb for t+1 early: independent of this step's MFMA results,
        // so it overlaps the MFMA tail instead of extending the epilogue.
        if (t + 1 < Sv) {
            *reinterpret_cast<uint2*>(&SH[wbuf + SW(eo)]) =
                make_uint2(pk_h2(ev_cur.x, ev_cur.y), pk_h2(ev_cur.z, ev_cur.w));
        }

        // epilogue: lane holds h[m=col][n = ti*16 + 4q + r]
        #pragma unroll
        for (int i = 0; i < 2; ++i) {
            f4v s = (i == 0) ? (aHe0 + aHo0) : (aHe1 + aHo1);
            const int ti = 2 * w + i;
            float hv[4];
            #pragma unroll
            for (int r = 0; r < 4; ++r)
                hv[r] = fast_tanh(s[r]);
            const int dl = ((ti & 1) * 2 + (q >> 1)) * 16 + col;
            const uint2 hu = make_uint2(pk_h2(hv[0], hv[1]), pk_h2(hv[2], hv[3]));
            const int oAH = (4 + (ti >> 1)) * 256 + dl * 4 + (q & 1) * 2;
            *reinterpret_cast<uint2*>(&SH[wbuf + SW(oAH)]) = hu;
            if (t == len_c - 1) snap[i] = hu;   // register snapshot, no LDS write
        }
        ev_cur = ev_next;
        __syncthreads();
    }

    // ---- write last-h snapshots to LF once ----
    #pragma unroll
    for (int i = 0; i < 2; ++i) {
        const int ti = 2 * w + i;
        const int dl = ((ti & 1) * 2 + (q >> 1)) * 16 + col;
        const int oLH = (ti >> 1) * 256 + dl * 4 + (q & 1) * 2;
        *reinterpret_cast<uint2*>(&LF[SW(oLH)]) = snap[i];
    }
    __syncthreads();

    // ---- fused FC1 (MFMA, f16 hi+lo) on LF ----
    f4v fH0, fH1, fL0, fL1;
    {
        float4 bb0 = *(const float4*)&b1[(2 * w) * 16 + 4 * q];
        float4 bb1 = *(const float4*)&b1[(2 * w + 1) * 16 + 4 * q];
        fH0 = (f4v){bb0.x, bb0.y, bb0.z, bb0.w};
        fH1 = (f4v){bb1.x, bb1.y, bb1.z, bb1.w};
        f4v z = {0.f, 0.f, 0.f, 0.f};
        fL0 = z; fL1 = z;
    }
    #pragma unroll
    for (int kb = 0; kb < 8; ++kb) {
        hfrag ah = *reinterpret_cast<const hfrag*>(&LF[SW(kb * 256 + lane * 4)]);
        int fid0 = (kb * 16 + 2 * w) * 64 + lane;
        int fid1 = fid0 + 64;
        hfrag w0h = *reinterpret_cast<const hfrag*>(&wf1h[(size_t)fid0 * 4]);
        hfrag w1h = *reinterpret_cast<const hfrag*>(&wf1h[(size_t)fid1 * 4]);
        hfrag w0l = *reinterpret_cast<const hfrag*>(&wf1l[(size_t)fid0 * 4]);
        hfrag w1l = *reinterpret_cast<const hfrag*>(&wf1l[(size_t)fid1 * 4]);
        fH0 = __builtin_amdgcn_mfma_f32_16x16x32_f16(w0h, ah, fH0, 0, 0, 0);
        fH1 = __builtin_amdgcn_mfma_f32_16x16x32_f16(w1h, ah, fH1, 0, 0, 0);
        fL0 = __builtin_amdgcn_mfma_f32_16x16x32_f16(w0l, ah, fL0, 0, 0, 0);
        fL1 = __builtin_amdgcn_mfma_f32_16x16x32_f16(w1l, ah, fL1, 0, 0, 0);
    }

    // y = relu(...) into yb (aliases SH; step buffers dead, LF untouched)
    #pragma unroll
    for (int i = 0; i < 2; ++i) {
        int n0 = (2 * w + i) * 16 + 4 * q;
        f4v s = (i == 0) ? fH0 : fH1;
        f4v sl = (i == 0) ? fL0 : fL1;
        float4 yv;
        yv.x = fmaxf(s[0] + sl[0] * LO_DESCALE, 0.f);
        yv.y = fmaxf(s[1] + sl[1] * LO_DESCALE, 0.f);
        yv.z = fmaxf(s[2] + sl[2] * LO_DESCALE, 0.f);
        yv.w = fmaxf(s[3] + sl[3] * LO_DESCALE, 0.f);
        *reinterpret_cast<float4*>(&yb[col * 260 + n0]) = yv;
    }
    __syncthreads();

    // ---- FC2: 16 x 18 dots of length 256 ----
    if (tid < Mrows * Cv) {
        int r = tid & 15, cc = tid >> 4;
        float s = b2[cc];
        #pragma unroll 8
        for (int k4 = 0; k4 < Hv / 4; ++k4) {
            float4 yv = *reinterpret_cast<const float4*>(&yb[r * 260 + 4 * k4]);
            float4 wv2 = *(const float4*)&W2[cc * Hv + 4 * k4];
            s = fmaf(yv.x, wv2.x, s);
            s = fmaf(yv.y, wv2.y, s);
            s = fmaf(yv.z, wv2.z, s);
            s = fmaf(yv.w, wv2.w, s);
        }
        out[(rb + r) * Cv + cc] = s;
    }
}

extern "C" void kernel_launch(void* const* d_in, const int* in_sizes, int n_in,
                              void* d_out, int out_size, void* d_ws, size_t ws_size,
                              hipStream_t stream) {
    const int*   x_in  = (const int*)  d_in[0];
    const int*   x_len = (const int*)  d_in[1];
    const float* emb   = (const float*)d_in[2];
    const float* W_ih  = (const float*)d_in[3];
    const float* W_hh  = (const float*)d_in[4];
    const float* b_ih  = (const float*)d_in[5];
    const float* b_hh  = (const float*)d_in[6];
    const float* W1    = (const float*)d_in[7];
    const float* b1    = (const float*)d_in[8];
    const float* W2    = (const float*)d_in[9];
    const float* b2    = (const float*)d_in[10];
    float* out = (float*)d_out;

    unsigned* wfh  = (unsigned*)d_ws;         // 12288 frags * 16 B
    unsigned* wf1h = wfh  + 12288 * 4;        // 8192 * 16 B
    unsigned* wf1l = wf1h + 8192 * 4;         // 8192 * 16 B

    build_frags<<<80, 256, 0, stream>>>(W_ih, W_hh, W1, wfh, wf1h, wf1l);
    rnn_fused<<<Bv / Mrows, 512, 0, stream>>>(x_in, x_len, emb, wfh,
                                              wf1h, wf1l, b_ih, b_hh,
                                              b1, W2, b2, out);
}